// Round 1
// baseline (12.365 us; speedup 1.0000x reference)
//
#include <hip/hip_runtime.h>

// TimeEncoder: out0[b,l,:] = W[:, idx] + bias  where idx = relu(floor(ts[b,l+1]-ts[b,l]))
//              out1[b,l]   = ts[b,l]
// B=64, L=8192, N_TIME=100, OUT_DIM=8, PER_TIME=1.0 (division is a no-op)

#define N_TIME 100
#define OUT_DIM 8
#define BB 64
#define LL 8192

__global__ __launch_bounds__(256) void time_encoder_kernel(
    const float* __restrict__ ts,    // [B, L+1]
    const float* __restrict__ W,     // [OUT_DIM, N_TIME] row-major
    const float* __restrict__ bias,  // [OUT_DIM]
    float* __restrict__ out_emb,     // [B*L, OUT_DIM]
    float* __restrict__ out_ts)      // [B*L]
{
    // Wb[t][o] = W[o][t] + bias[o]; bonly = bias (jax one_hot OOB -> all-zero row)
    __shared__ __align__(16) float Wb[N_TIME][OUT_DIM];
    __shared__ __align__(16) float bonly[OUT_DIM];

    for (int i = threadIdx.x; i < N_TIME * OUT_DIM; i += blockDim.x) {
        int t = i >> 3;        // / OUT_DIM
        int o = i & 7;         // % OUT_DIM
        Wb[t][o] = W[o * N_TIME + t] + bias[o];
    }
    if (threadIdx.x < OUT_DIM) bonly[threadIdx.x] = bias[threadIdx.x];
    __syncthreads();

    int tid = blockIdx.x * blockDim.x + threadIdx.x;   // [0, B*L)
    int b = tid >> 13;    // / 8192
    int l = tid & 8191;   // % 8192

    const float* row = ts + (size_t)b * (LL + 1);
    float t0 = row[l];
    float t1 = row[l + 1];
    float dt = t1 - t0;                 // PER_TIME == 1.0
    int idx = (int)floorf(dt);
    if (idx < 0) idx = 0;               // relu

    const float* src = (idx < N_TIME) ? &Wb[idx][0] : &bonly[0];
    float4 v0 = *reinterpret_cast<const float4*>(src);
    float4 v1 = *reinterpret_cast<const float4*>(src + 4);

    float4* o4 = reinterpret_cast<float4*>(out_emb + (size_t)tid * OUT_DIM);
    o4[0] = v0;
    o4[1] = v1;

    out_ts[tid] = t0;
}

extern "C" void kernel_launch(void* const* d_in, const int* in_sizes, int n_in,
                              void* d_out, int out_size, void* d_ws, size_t ws_size,
                              hipStream_t stream) {
    // d_in order: input(int64, unused), timestamp(f32 [B,L+1]), W(f32 [8,100]),
    //             b(f32 [8]), train(int, unused)
    const float* ts   = (const float*)d_in[1];
    const float* W    = (const float*)d_in[2];
    const float* bias = (const float*)d_in[3];

    float* out_emb = (float*)d_out;                         // B*L*8 floats
    float* out_ts  = (float*)d_out + (size_t)BB * LL * OUT_DIM;  // B*L floats

    const int total  = BB * LL;            // 524288 threads
    const int block  = 256;
    const int grid   = total / block;      // 2048 blocks

    time_encoder_kernel<<<grid, block, 0, stream>>>(ts, W, bias, out_emb, out_ts);
}

// Round 2
// 12.105 us; speedup vs baseline: 1.0214x; 1.0214x over previous
//
#include <hip/hip_runtime.h>

// TimeEncoder: out0[b,l,:] = W[:, idx] + bias  where idx = relu(floor(ts[b,l+1]-ts[b,l]))
//              out1[b,l]   = ts[b,l]
// B=64, L=8192, N_TIME=100, OUT_DIM=8, PER_TIME=1.0 (division is a no-op)

#define N_TIME 100
#define OUT_DIM 8
#define BB 64
#define LL 8192
#define BLOCK 256
#define EPT 2   // elements per thread

__global__ __launch_bounds__(BLOCK) void time_encoder_kernel(
    const float* __restrict__ ts,    // [B, L+1]
    const float* __restrict__ W,     // [OUT_DIM, N_TIME] row-major
    const float* __restrict__ bias,  // [OUT_DIM]
    float* __restrict__ out_emb,     // [B*L, OUT_DIM]
    float* __restrict__ out_ts)      // [B*L]
{
    // Split table: T0[t] = W[0:4, t]+b[0:4], T1[t] = W[4:8, t]+b[4:8].
    // Row N_TIME = bias only (jax one_hot OOB -> all-zero row @ W + b).
    // Two float4 arrays instead of one [t][8] array: first-word bank spread
    // 4 groups -> 8 groups (~16-way -> ~8-way read conflict).
    __shared__ __align__(16) float4 T0[N_TIME + 1];
    __shared__ __align__(16) float4 T1[N_TIME + 1];

    float* t0f = reinterpret_cast<float*>(T0);
    float* t1f = reinterpret_cast<float*>(T1);

    // Coalesced preload: thread reads W[i] linearly (L2-resident after warmup).
    for (int i = threadIdx.x; i < N_TIME * OUT_DIM; i += BLOCK) {
        int o = i / N_TIME;           // compiler magic-mul
        int t = i - o * N_TIME;
        float v = W[i] + bias[o];
        if (o < 4) t0f[t * 4 + o]       = v;
        else       t1f[t * 4 + (o - 4)] = v;
    }
    if (threadIdx.x < OUT_DIM) {      // OOB row = bias only
        int o = threadIdx.x;
        float v = bias[o];
        if (o < 4) t0f[N_TIME * 4 + o]       = v;
        else       t1f[N_TIME * 4 + (o - 4)] = v;
    }
    __syncthreads();

    const int nthreads = gridDim.x * BLOCK;
    int gid = blockIdx.x * BLOCK + threadIdx.x;

    #pragma unroll
    for (int e = 0; e < EPT; ++e) {
        int tid = gid + e * nthreads;          // grid-stride keeps stores coalesced
        int b = tid >> 13;                     // / 8192
        int l = tid & 8191;                    // % 8192
        const float* row = ts + (size_t)b * (LL + 1);
        float x0 = row[l];
        float x1 = row[l + 1];
        int idx = (int)floorf(x1 - x0);        // PER_TIME == 1.0
        idx = max(idx, 0);                     // relu
        idx = min(idx, N_TIME);                // OOB -> bias row

        float4 v0 = T0[idx];
        float4 v1 = T1[idx];

        float4* o4 = reinterpret_cast<float4*>(out_emb + (size_t)tid * OUT_DIM);
        o4[0] = v0;
        o4[1] = v1;
        out_ts[tid] = x0;
    }
}

extern "C" void kernel_launch(void* const* d_in, const int* in_sizes, int n_in,
                              void* d_out, int out_size, void* d_ws, size_t ws_size,
                              hipStream_t stream) {
    const float* ts   = (const float*)d_in[1];
    const float* W    = (const float*)d_in[2];
    const float* bias = (const float*)d_in[3];

    float* out_emb = (float*)d_out;                              // B*L*8 floats
    float* out_ts  = (float*)d_out + (size_t)BB * LL * OUT_DIM;  // B*L floats

    const int total = BB * LL;                 // 524288 elements
    const int grid  = total / (BLOCK * EPT);   // 1024 blocks

    time_encoder_kernel<<<grid, BLOCK, 0, stream>>>(ts, W, bias, out_emb, out_ts);
}